// Round 1
// baseline (282.089 us; speedup 1.0000x reference)
//
#include <hip/hip_runtime.h>

#define NB 256
#define SS 512
#define LL 128

template <int P>
__device__ __forceinline__ float swzf(float x) {
    return __int_as_float(__builtin_amdgcn_ds_swizzle(__float_as_int(x), P));
}

// Forward algorithm in exp-domain. One workgroup (512 thr, 8 waves) per batch.
// Lane layout: wave w, lane l -> j = 16*w + (l&15), i-quarter q = l>>4.
// E[i][j] fragment (32 values) lives in registers. u vector in LDS
// (bank-padded stride 36 floats per 32), double-buffered, 1 barrier/step.
__global__ __launch_bounds__(512) void crf_fwd_kernel(
    const float* __restrict__ feats,    // (B,S,L)
    const float* __restrict__ start_t,  // (L)
    const float* __restrict__ trans,    // (L,L)
    const int* __restrict__ mask,       // (B,S)
    float* __restrict__ logden)         // (B)
{
    const int b = blockIdx.x;
    const int tid = threadIdx.x;
    const int wave = tid >> 6;
    const int lane = tid & 63;
    const int jloc = lane & 15;
    const int q = lane >> 4;
    const int j = wave * 16 + jloc;

    __shared__ __align__(16) float urow[2][144];  // 4 chunks * (32 + 4 pad)
    __shared__ __align__(16) int lmask[SS];       // lmask[i] = mask[b][i+1]
    __shared__ float pm[8];

    lmask[tid] = (tid + 1 < SS) ? mask[b * SS + tid + 1] : 0;

    // E fragment: e[k] = exp(T[32q+k][j])
    float e[32];
    {
        const float* tb = trans + j;
#pragma unroll
        for (int k = 0; k < 32; ++k) e[k] = __expf(tb[(32 * q + k) * LL]);
    }

    const float* fbj = feats + (size_t)b * SS * LL + j;
    const int wi = ((j >> 5) * 36) + (j & 31);

    float M = 0.0f;
    float u = __expf(start_t[j] + fbj[0]);  // alpha_0 in exp domain, M=0
    if (q == 0) urow[0][wi] = u;
    __syncthreads();

    auto loadg = [&](int tbase) -> float {
        int tr = tbase + q;
        tr = tr < SS ? tr : (SS - 1);
        return fbj[tr * LL];
    };

    const float4* vbuf0 = reinterpret_cast<const float4*>(&urow[0][q * 36]);
    const float4* vbuf1 = reinterpret_cast<const float4*>(&urow[1][q * 36]);

    // steps t=1..512 (t=512 is a dummy with mask forced 0); groups of 4,
    // 2 groups per iteration, feature rows prefetched 2 groups ahead.
    float f0 = loadg(1);
    float f1 = loadg(5);

    for (int it = 0; it < 64; ++it) {
        const int tb0 = 8 * it + 1;
        float fn0 = loadg(tb0 + 8);
        float fn1 = loadg(tb0 + 12);

#pragma unroll
        for (int half = 0; half < 2; ++half) {
            const float fgrp = half ? f1 : f0;
            const int tbase = tb0 + 4 * half;
            const int4 mm = *reinterpret_cast<const int4*>(&lmask[tbase - 1]);
#pragma unroll
            for (int s = 0; s < 4; ++s) {
                __syncthreads();
                const float4* vb = (s & 1) ? vbuf1 : vbuf0;
                float4 vv[8];
#pragma unroll
                for (int r = 0; r < 8; ++r) vv[r] = vb[r];
                float a0 = 0.f, a1 = 0.f, a2 = 0.f, a3 = 0.f;
#pragma unroll
                for (int r = 0; r < 8; ++r) {
                    a0 = fmaf(vv[r].x, e[4 * r + 0], a0);
                    a1 = fmaf(vv[r].y, e[4 * r + 1], a1);
                    a2 = fmaf(vv[r].z, e[4 * r + 2], a2);
                    a3 = fmaf(vv[r].w, e[4 * r + 3], a3);
                }
                float acc = (a0 + a1) + (a2 + a3);
                acc += swzf<0x401F>(acc);        // + partner quarter (xor 16)
                acc += __shfl_xor(acc, 32, 64);  // + other half (xor 32)
                const float ft = __shfl(fgrp, jloc + 16 * s, 64);
                const float r_ = __expf(ft) * acc;
                const int mk = (s == 0) ? mm.x : (s == 1) ? mm.y
                             : (s == 2) ? mm.z : mm.w;
                u = mk ? r_ : u;  // masked step: alpha unchanged
                if (s == 3) {     // rescale once per 4 steps (growth <= ~1e17)
                    float wm = u;
                    wm = fmaxf(wm, swzf<0x041F>(wm));
                    wm = fmaxf(wm, swzf<0x081F>(wm));
                    wm = fmaxf(wm, swzf<0x101F>(wm));
                    wm = fmaxf(wm, swzf<0x201F>(wm));
                    if (lane == 0) pm[wave] = wm;
                    __syncthreads();
                    float c = pm[0];
#pragma unroll
                    for (int w2 = 1; w2 < 8; ++w2) c = fmaxf(c, pm[w2]);
                    u = u / c;
                    M += __logf(c);
                }
                if (q == 0) urow[(s + 1) & 1][wi] = u;
            }
        }
        f0 = fn0;
        f1 = fn1;
    }

    __syncthreads();
    // final state (t=512) is in buffer 0
    if (wave == 0) {
        const int i2 = lane + 64;
        // end_transitions folded in by the numerator kernel? No: here.
        float ua = urow[0][((lane >> 5) * 36) + (lane & 31)];
        float ub = urow[0][((i2 >> 5) * 36) + (i2 & 31)];
        float sv = ua * __expf(logden ? 0.f : 0.f) * 0.f;  // placeholder removed below
        (void)sv;
        // computed properly:
        float ea = 0.f, eb = 0.f;
        // end transitions passed via logden? no — loaded directly:
        ea = ua;  eb = ub;  // values multiplied by exp(end) below in caller path
        // NOTE: end_t applied here via global pointer stored in pm? -> simpler:
        // we re-load end transitions through the trans pointer trick is wrong;
        // see crf_fwd_kernel2 wrapper below.
        if (lane == 0) logden[b] = M;           // M stashed
        urow[1][((lane >> 5) * 36) + (lane & 31)] = ua;   // not needed
    }
    // (epilogue completed in crf_fin_kernel to keep this kernel's params tidy)
    __syncthreads();
    if (wave == 1) {
        // store final u (both halves) densely into logden-adjacent scratch?
        // Not needed: crf_fin_kernel below re-reads nothing from LDS.
    }
}

// Epilogue + numerator + loss. One block (256 thr) per batch.
// Recomputes log_den's final LSE-over-end? No — crf_fwd stored only M, so the
// final sum over u must happen in crf_fwd. To keep correctness simple we do
// the whole end-transition fold in crf_fwd via end_t parameter in v2 below.
__global__ __launch_bounds__(256) void crf_num_kernel(
    const float* __restrict__ feats,
    const float* __restrict__ start_t,
    const float* __restrict__ end_t,
    const float* __restrict__ trans,
    const float* __restrict__ conf,
    const int* __restrict__ mask,
    const int* __restrict__ labels,
    const float* __restrict__ logden,
    float* __restrict__ out)
{
    const int b = blockIdx.x;
    const int tid = threadIdx.x;
    const int* lb = labels + b * SS;
    const int* mb = mask + b * SS;
    const float* fb = feats + (size_t)b * SS * LL;

    float term = 0.f;
    int cnt = 0;
#pragma unroll
    for (int rr = 0; rr < 2; ++rr) {
        int t = tid + rr * 256;
        int l = lb[t];
        if ((unsigned)l >= LL) l = 0;
        int m = mb[t];
        cnt += (m != 0);
        if (t == 0) {
            term += start_t[l] + fb[l];
        } else if (m != 0) {
            int lp = lb[t - 1];
            if ((unsigned)lp >= LL) lp = 0;
            term += trans[lp * LL + l] + fb[t * LL + l];
        }
    }
#pragma unroll
    for (int o = 1; o < 64; o <<= 1) {
        term += __shfl_xor(term, o, 64);
        cnt += __shfl_xor(cnt, o, 64);
    }
    __shared__ float sred[4];
    __shared__ int cred[4];
    if ((tid & 63) == 0) { sred[tid >> 6] = term; cred[tid >> 6] = cnt; }
    __syncthreads();
    if (tid == 0) {
        float tot = (sred[0] + sred[1]) + (sred[2] + sred[3]);
        int c = cred[0] + cred[1] + cred[2] + cred[3];
        int sl = c - 1;
        sl = sl < 0 ? 0 : (sl >= SS ? SS - 1 : sl);
        int lt = lb[sl];
        if ((unsigned)lt >= LL) lt = 0;
        float logn = tot + end_t[lt];
        float loss = (logden[b] - logn) * conf[b] * (1.0f / NB);
        atomicAdd(out, loss);
    }
}

// v2 of forward kernel with end-transition epilogue done properly in-kernel.
__global__ __launch_bounds__(512) void crf_fwd_kernel2(
    const float* __restrict__ feats,
    const float* __restrict__ start_t,
    const float* __restrict__ end_t,
    const float* __restrict__ trans,
    const int* __restrict__ mask,
    float* __restrict__ logden)
{
    const int b = blockIdx.x;
    const int tid = threadIdx.x;
    const int wave = tid >> 6;
    const int lane = tid & 63;
    const int jloc = lane & 15;
    const int q = lane >> 4;
    const int j = wave * 16 + jloc;

    __shared__ __align__(16) float urow[2][144];
    __shared__ __align__(16) int lmask[SS];
    __shared__ float pm[8];

    lmask[tid] = (tid + 1 < SS) ? mask[b * SS + tid + 1] : 0;

    float e[32];
    {
        const float* tb = trans + j;
#pragma unroll
        for (int k = 0; k < 32; ++k) e[k] = __expf(tb[(32 * q + k) * LL]);
    }

    const float* fbj = feats + (size_t)b * SS * LL + j;
    const int wi = ((j >> 5) * 36) + (j & 31);

    float M = 0.0f;
    float u = __expf(start_t[j] + fbj[0]);
    if (q == 0) urow[0][wi] = u;
    __syncthreads();

    auto loadg = [&](int tbase) -> float {
        int tr = tbase + q;
        tr = tr < SS ? tr : (SS - 1);
        return fbj[tr * LL];
    };

    const float4* vbuf0 = reinterpret_cast<const float4*>(&urow[0][q * 36]);
    const float4* vbuf1 = reinterpret_cast<const float4*>(&urow[1][q * 36]);

    float f0 = loadg(1);
    float f1 = loadg(5);

    for (int it = 0; it < 64; ++it) {
        const int tb0 = 8 * it + 1;
        float fn0 = loadg(tb0 + 8);
        float fn1 = loadg(tb0 + 12);

#pragma unroll
        for (int half = 0; half < 2; ++half) {
            const float fgrp = half ? f1 : f0;
            const int tbase = tb0 + 4 * half;
            const int4 mm = *reinterpret_cast<const int4*>(&lmask[tbase - 1]);
#pragma unroll
            for (int s = 0; s < 4; ++s) {
                __syncthreads();
                const float4* vb = (s & 1) ? vbuf1 : vbuf0;
                float4 vv[8];
#pragma unroll
                for (int r = 0; r < 8; ++r) vv[r] = vb[r];
                float a0 = 0.f, a1 = 0.f, a2 = 0.f, a3 = 0.f;
#pragma unroll
                for (int r = 0; r < 8; ++r) {
                    a0 = fmaf(vv[r].x, e[4 * r + 0], a0);
                    a1 = fmaf(vv[r].y, e[4 * r + 1], a1);
                    a2 = fmaf(vv[r].z, e[4 * r + 2], a2);
                    a3 = fmaf(vv[r].w, e[4 * r + 3], a3);
                }
                float acc = (a0 + a1) + (a2 + a3);
                acc += swzf<0x401F>(acc);
                acc += __shfl_xor(acc, 32, 64);
                const float ft = __shfl(fgrp, jloc + 16 * s, 64);
                const float r_ = __expf(ft) * acc;
                const int mk = (s == 0) ? mm.x : (s == 1) ? mm.y
                             : (s == 2) ? mm.z : mm.w;
                u = mk ? r_ : u;
                if (s == 3) {
                    float wm = u;
                    wm = fmaxf(wm, swzf<0x041F>(wm));
                    wm = fmaxf(wm, swzf<0x081F>(wm));
                    wm = fmaxf(wm, swzf<0x101F>(wm));
                    wm = fmaxf(wm, swzf<0x201F>(wm));
                    if (lane == 0) pm[wave] = wm;
                    __syncthreads();
                    float c = pm[0];
#pragma unroll
                    for (int w2 = 1; w2 < 8; ++w2) c = fmaxf(c, pm[w2]);
                    u = u / c;
                    M += __logf(c);
                }
                if (q == 0) urow[(s + 1) & 1][wi] = u;
            }
        }
        f0 = fn0;
        f1 = fn1;
    }

    __syncthreads();
    if (wave == 0) {
        const int i2 = lane + 64;
        float ua = urow[0][((lane >> 5) * 36) + (lane & 31)];
        float ub = urow[0][((i2 >> 5) * 36) + (i2 & 31)];
        float sv = ua * __expf(end_t[lane]) + ub * __expf(end_t[i2]);
        sv += swzf<0x041F>(sv);
        sv += swzf<0x081F>(sv);
        sv += swzf<0x101F>(sv);
        sv += swzf<0x201F>(sv);
        sv += swzf<0x401F>(sv);
        sv += __shfl_xor(sv, 32, 64);
        if (lane == 0) logden[b] = M + __logf(sv);
    }
}

extern "C" void kernel_launch(void* const* d_in, const int* in_sizes, int n_in,
                              void* d_out, int out_size, void* d_ws, size_t ws_size,
                              hipStream_t stream) {
    const float* feats  = (const float*)d_in[0];
    const float* startt = (const float*)d_in[1];
    const float* endt   = (const float*)d_in[2];
    const float* trans  = (const float*)d_in[3];
    const float* conf   = (const float*)d_in[4];
    const int*   mask   = (const int*)d_in[5];
    const int*   labels = (const int*)d_in[6];
    float* out = (float*)d_out;
    float* logden = (float*)d_ws;  // 256 floats

    hipMemsetAsync(d_out, 0, sizeof(float), stream);
    hipLaunchKernelGGL(crf_fwd_kernel2, dim3(NB), dim3(512), 0, stream,
                       feats, startt, endt, trans, mask, logden);
    hipLaunchKernelGGL(crf_num_kernel, dim3(NB), dim3(256), 0, stream,
                       feats, startt, endt, trans, conf, mask, labels, logden, out);
}

// Round 2
// 225.703 us; speedup vs baseline: 1.2498x; 1.2498x over previous
//
#include <hip/hip_runtime.h>
#include <math.h>

#define NB 256
#define SS 512
#define LL 128

template <int P>
__device__ __forceinline__ float swzf(float x) {
    return __int_as_float(__builtin_amdgcn_ds_swizzle(__float_as_int(x), P));
}

// Fused CRF loss. One workgroup (512 thr, 8 waves) per batch.
// Forward-backward split: Z = sum_j alpha_255[j] * beta_255[j].
//   waves 0-3: forward chain,  rounds r=0..255 process t=r+1   (r=255 dummy, mask=0)
//   waves 4-7: backward chain, rounds r=0..255 process t=511-r
// Per chain: lane task (col = 32*wg + lane&31, i-half = lane>>5), 64 FMA/round,
// exp(trans) fragment in 64 VGPRs, one shfl_xor(32) reduce, 1 barrier/round
// (double-buffered LDS state), exponent rescale (exact) every 8 rounds.
__global__ __launch_bounds__(512, 1) void crf_fused_kernel(
    const float* __restrict__ feats,    // (B,S,L)
    const float* __restrict__ start_t,  // (L)
    const float* __restrict__ end_t,    // (L)
    const float* __restrict__ trans,    // (L,L)
    const float* __restrict__ conf,     // (B)
    const int* __restrict__ mask,       // (B,S)
    const int* __restrict__ labels,     // (B,S)
    float* __restrict__ out)            // scalar (pre-zeroed)
{
    const int b = blockIdx.x;
    const int tid = threadIdx.x;
    const int wave = tid >> 6;
    const int lane = tid & 63;
    const int jl = lane & 31;
    const int qh = lane >> 5;       // which 64-wide half of the contraction dim
    const int grp = wave >> 2;      // 0 = forward, 1 = backward
    const int wg = wave & 3;
    const int col = 32 * wg + jl;   // j for fwd, i for bwd

    __shared__ __align__(16) float stA[2][LL];  // fwd alpha exchange (dbuf)
    __shared__ __align__(16) float stB[2][LL];  // bwd w = ef*beta exchange (dbuf)
    __shared__ int mS[2][256];
    __shared__ float pm[8];
    __shared__ float sA[LL];
    __shared__ float sB[LL];
    __shared__ int eI[2];
    __shared__ float ldsh;
    __shared__ float nred[8];
    __shared__ int cred[8];

    // mask staging: mS[0][r] = mask[b][r+1] (fwd), mS[1][r] = mask[b][511-r] (bwd)
    {
        int r = tid & 255;
        if (tid < 256) mS[0][r] = (r < 255) ? mask[b * SS + r + 1] : 0;
        else           mS[1][r] = mask[b * SS + 511 - r];
    }

    // exp(transition) fragment: fwd lane needs E[i_half][j=col] (column slice),
    // bwd lane needs E[i=col][j_half] (row slice, vectorizable).
    float e[64];
    if (grp == 0) {
#pragma unroll
        for (int k = 0; k < 64; ++k)
            e[k] = __expf(trans[(64 * qh + k) * LL + col]);
    } else {
        const float4* tr4 = reinterpret_cast<const float4*>(trans + col * LL + 64 * qh);
#pragma unroll
        for (int k = 0; k < 16; ++k) {
            float4 t4 = tr4[k];
            e[4 * k + 0] = __expf(t4.x);
            e[4 * k + 1] = __expf(t4.y);
            e[4 * k + 2] = __expf(t4.z);
            e[4 * k + 3] = __expf(t4.w);
        }
    }

    const float* fcol = feats + (size_t)b * SS * LL + col;

    // chain state in exp domain (duplicated across the two qh halves)
    float u;
    if (grp == 0) u = __expf(start_t[col] + fcol[0]);   // alpha_0
    else          u = __expf(end_t[col]);               // beta_511
    int eacc = 0;  // power-of-2 rescale exponent accumulator

    // per-lane feature prefetch pipeline (8 rounds ahead)
    float fr[8], fr2[8];
#pragma unroll
    for (int k = 0; k < 8; ++k)
        fr[k] = (grp == 0) ? fcol[(1 + k) * LL] : fcol[(511 - k) * LL];

    float* const myW0 = (grp == 0) ? stA[0] : stB[0];
    float* const myW1 = (grp == 0) ? stA[1] : stB[1];
    const float4* const myR0 =
        reinterpret_cast<const float4*>(((grp == 0) ? stA[0] : stB[0]) + 64 * qh);
    const float4* const myR1 =
        reinterpret_cast<const float4*>(((grp == 0) ? stA[1] : stB[1]) + 64 * qh);
    const int* const myM = mS[grp];

    for (int blk = 0; blk < 32; ++blk) {
        // prefetch next block's features (always in-bounds: t in [249, 264])
#pragma unroll
        for (int k = 0; k < 8; ++k) {
            int rn = 8 * (blk + 1) + k;
            fr2[k] = (grp == 0) ? fcol[(1 + rn) * LL] : fcol[(511 - rn) * LL];
        }
#pragma unroll
        for (int s = 0; s < 8; ++s) {
            const int r = 8 * blk + s;
            float* wptr = (r & 1) ? myW1 : myW0;
            const float4* rptr = (r & 1) ? myR1 : myR0;
            // fwd publishes alpha_{t-1}; bwd publishes w = exp(f_t)*beta_t
            float wval = (grp == 0) ? u : __expf(fr[s]) * u;
            wptr[col] = wval;  // both qh halves write same value: benign
            __syncthreads();
            float4 vv[16];
#pragma unroll
            for (int k = 0; k < 16; ++k) vv[k] = rptr[k];
            float a0 = 0.f, a1 = 0.f, a2 = 0.f, a3 = 0.f;
#pragma unroll
            for (int k = 0; k < 16; ++k) {
                a0 = fmaf(vv[k].x, e[4 * k + 0], a0);
                a1 = fmaf(vv[k].y, e[4 * k + 1], a1);
                a2 = fmaf(vv[k].z, e[4 * k + 2], a2);
                a3 = fmaf(vv[k].w, e[4 * k + 3], a3);
            }
            float acc = (a0 + a1) + (a2 + a3);
            acc += __shfl_xor(acc, 32);  // combine the two i-halves
            float un = (grp == 0) ? __expf(fr[s]) * acc : acc;
            int mk = myM[r];
            u = mk ? un : u;
            if (s == 7) {
                // exponent rescale (exact): growth over 8 rounds < 2^96, safe
                float wm = u;
                wm = fmaxf(wm, swzf<0x041F>(wm));
                wm = fmaxf(wm, swzf<0x081F>(wm));
                wm = fmaxf(wm, swzf<0x101F>(wm));
                wm = fmaxf(wm, swzf<0x201F>(wm));
                if (lane == 0) pm[wave] = wm;
                __syncthreads();
                float c = fmaxf(fmaxf(pm[4 * grp + 0], pm[4 * grp + 1]),
                                fmaxf(pm[4 * grp + 2], pm[4 * grp + 3]));
                int ex;
                frexpf(c, &ex);
                u = ldexpf(u, -ex);
                eacc += ex;
            }
        }
#pragma unroll
        for (int k = 0; k < 8; ++k) fr[k] = fr2[k];
    }

    // ---- combine: Z = sum_j alpha_255[j] * beta_255[j] * 2^(eF+eB) ----
    __syncthreads();
    if (grp == 0) sA[col] = u; else sB[col] = u;
    if (tid == 0)   eI[0] = eacc;
    if (tid == 256) eI[1] = eacc;
    __syncthreads();
    if (wave == 0) {
        float p = sA[lane] * sB[lane] + sA[lane + 64] * sB[lane + 64];
        p += __shfl_xor(p, 1);
        p += __shfl_xor(p, 2);
        p += __shfl_xor(p, 4);
        p += __shfl_xor(p, 8);
        p += __shfl_xor(p, 16);
        p += __shfl_xor(p, 32);
        if (lane == 0)
            ldsh = logf(p) + 0.69314718055994531f * (float)(eI[0] + eI[1]);
    }

    // ---- numerator (gold path score), fused: thread tid handles t = tid ----
    const int* lb = labels + b * SS;
    const int* mb = mask + b * SS;
    const float* fb = feats + (size_t)b * SS * LL;
    float term = 0.f;
    int cnt = 0;
    {
        int t = tid;
        int l = lb[t];
        if ((unsigned)l >= LL) l = 0;
        int m = mb[t];
        cnt = (m != 0);
        if (t == 0) {
            term = start_t[l] + fb[l];
        } else if (m) {
            int lp = lb[t - 1];
            if ((unsigned)lp >= LL) lp = 0;
            term = trans[lp * LL + l] + fb[t * LL + l];
        }
    }
#pragma unroll
    for (int o = 1; o < 64; o <<= 1) {
        term += __shfl_xor(term, o);
        cnt += __shfl_xor(cnt, o);
    }
    if (lane == 0) { nred[wave] = term; cred[wave] = cnt; }
    __syncthreads();
    if (tid == 0) {
        float tot = 0.f;
        int c = 0;
#pragma unroll
        for (int w = 0; w < 8; ++w) { tot += nred[w]; c += cred[w]; }
        int sl = c - 1;
        sl = sl < 0 ? 0 : (sl >= SS ? SS - 1 : sl);
        int lt = lb[sl];
        if ((unsigned)lt >= LL) lt = 0;
        float logn = tot + end_t[lt];
        float loss = (ldsh - logn) * conf[b] * (1.0f / NB);
        atomicAdd(out, loss);
    }
}

extern "C" void kernel_launch(void* const* d_in, const int* in_sizes, int n_in,
                              void* d_out, int out_size, void* d_ws, size_t ws_size,
                              hipStream_t stream) {
    const float* feats  = (const float*)d_in[0];
    const float* startt = (const float*)d_in[1];
    const float* endt   = (const float*)d_in[2];
    const float* trans  = (const float*)d_in[3];
    const float* conf   = (const float*)d_in[4];
    const int*   mask   = (const int*)d_in[5];
    const int*   labels = (const int*)d_in[6];
    float* out = (float*)d_out;

    hipMemsetAsync(d_out, 0, sizeof(float), stream);
    hipLaunchKernelGGL(crf_fused_kernel, dim3(NB), dim3(512), 0, stream,
                       feats, startt, endt, trans, conf, mask, labels, out);
}

// Round 3
// 209.951 us; speedup vs baseline: 1.3436x; 1.0750x over previous
//
#include <hip/hip_runtime.h>
#include <hip/hip_bf16.h>
#include <math.h>

#define NB 256
#define SS 512
#define LL 128

typedef short bf16x8 __attribute__((ext_vector_type(8)));
typedef float f32x4 __attribute__((ext_vector_type(4)));

template <int P>
__device__ __forceinline__ float swzf(float x) {
    return __int_as_float(__builtin_amdgcn_ds_swizzle(__float_as_int(x), P));
}
__device__ __forceinline__ short f2bf(float f) {
    __hip_bfloat16 h = __float2bfloat16(f);
    short s;
    __builtin_memcpy(&s, &h, 2);
    return s;
}
__device__ __forceinline__ float bf2f(short s) {
    return __int_as_float(((int)(unsigned short)s) << 16);
}

// One block (256 thr, 4 waves) = one chain (fwd or bwd) of one batch.
// grid = 512: blocks 0..255 fwd, 256..511 bwd. 2 blocks/CU.
// Per round: publish u (bf16, 1 ds_write_b16) -> barrier -> read A-frags
// (4 broadcast ds_read_b128) -> 8 MFMAs/wave (wave owns N-tiles 2w,2w+1;
// A rows all equal u so every C row is the matvec) -> exp/mask/select.
// Features pre-staged to LDS as bf16 (2 stages x 128 rows); no global
// loads in the loop (syncthreads drains vmcnt). Rescale every 8 rounds:
// each wave recomputes the same power-of-2 scale from the shared image.
__global__ __launch_bounds__(256, 2) void crf_chain_kernel(
    const float* __restrict__ feats,    // (B,S,L)
    const float* __restrict__ start_t,  // (L)
    const float* __restrict__ end_t,    // (L)
    const float* __restrict__ trans,    // (L,L)
    const int* __restrict__ mask,       // (B,S)
    const int* __restrict__ labels,     // (B,S)
    float* __restrict__ ws)             // av[256*128] bv[256*128] eF[256] eB[256] lognum[256]
{
    const int bid = blockIdx.x;
    const int b = bid & 255;
    const int isB = bid >> 8;  // 0 = forward chain, 1 = backward chain
    const int tid = threadIdx.x;
    const int w = tid >> 6;
    const int L = tid & 63;
    const int l15 = L & 15;
    const int g = L >> 4;
    const int myNt = 2 * w + (g & 1);
    const int p_own = 16 * myNt + l15;  // owned position (valid for g<2; g>=2 dup)

    __shared__ __align__(16) short img[2][LL];   // u image, bf16, double-buffered
    __shared__ __align__(16) short fS[128 * LL]; // staged features, bf16 (32 KB)
    __shared__ int lmask[SS];
    __shared__ float nred[4];
    __shared__ int cred[4];

    float* av = ws;
    float* bv = ws + NB * LL;
    float* eFa = ws + 2 * NB * LL;
    float* eBa = eFa + NB;
    float* lognum = eBa + NB;

    const float* fb = feats + (size_t)b * SS * LL;

    // ---- build exp(transition) B-fragments (wave owns N-tiles 2w, 2w+1) ----
    // fwd: B[k][n] = exp(T[k][n]); bwd: B[k=j][n=i] = exp(T[i][j]) (= T^T)
    bf16x8 Bf[4][2];
#pragma unroll
    for (int kt = 0; kt < 4; ++kt) {
#pragma unroll
        for (int jj = 0; jj < 2; ++jj) {
            int n = 16 * (2 * w + jj) + l15;
            bf16x8 fr;
#pragma unroll
            for (int j2 = 0; j2 < 8; ++j2) {
                int k = 32 * kt + 8 * g + j2;
                float v = isB ? trans[n * LL + k] : trans[k * LL + n];
                fr[j2] = f2bf(__expf(v));
            }
            Bf[kt][jj] = fr;
        }
    }

    // ---- stage masks ----
    lmask[tid] = mask[b * SS + tid];
    lmask[tid + 256] = mask[b * SS + tid + 256];

    // ---- chain state init (exp domain) ----
    float x;
    if (isB) x = __expf(end_t[p_own]);                 // beta_511
    else     x = __expf(start_t[p_own] + fb[p_own]);   // alpha_0
    int eacc = 0;

    for (int r = 0; r < 256; ++r) {
        // ---- feature staging: 128 rows of bf16 per stage ----
        if ((r & 127) == 0) {
            if (r) __syncthreads();  // all waves done reading prior stage
            const int s = r >> 7;
#pragma unroll
            for (int q = 0; q < 16; ++q) {
                int v = tid + 256 * q;     // float4 index in [0, 4096)
                int slot = v >> 5;
                int pos4 = v & 31;
                int t = isB ? (511 - (128 * s + slot)) : (1 + 128 * s + slot);
                const float4 f4 = *(const float4*)(fb + (size_t)t * LL + 4 * pos4);
                short4 o;
                o.x = f2bf(f4.x); o.y = f2bf(f4.y); o.z = f2bf(f4.z); o.w = f2bf(f4.w);
                *((short4*)&fS[slot * LL + 4 * pos4]) = o;
            }
            __syncthreads();
        }

        const int t = isB ? (511 - r) : (r + 1);
        float ft = bf2f(fS[(r & 127) * LL + p_own]);
        int mt = lmask[t];
        if (r == 255 && !isB) mt = 0;  // fwd dummy round

        // publish: fwd publishes alpha_{t-1}; bwd publishes exp(f_t)*beta_t
        float pub = isB ? __expf(ft) * x : x;
        if (g < 2) img[r & 1][p_own] = f2bf(pub);
        __syncthreads();

        const bf16x8* ip = (const bf16x8*)(&img[r & 1][0]);
        bf16x8 a0 = ip[g], a1 = ip[4 + g], a2 = ip[8 + g], a3 = ip[12 + g];
        f32x4 c0 = {0.f, 0.f, 0.f, 0.f}, c1 = {0.f, 0.f, 0.f, 0.f};
        c0 = __builtin_amdgcn_mfma_f32_16x16x32_bf16(a0, Bf[0][0], c0, 0, 0, 0);
        c1 = __builtin_amdgcn_mfma_f32_16x16x32_bf16(a0, Bf[0][1], c1, 0, 0, 0);
        c0 = __builtin_amdgcn_mfma_f32_16x16x32_bf16(a1, Bf[1][0], c0, 0, 0, 0);
        c1 = __builtin_amdgcn_mfma_f32_16x16x32_bf16(a1, Bf[1][1], c1, 0, 0, 0);
        c0 = __builtin_amdgcn_mfma_f32_16x16x32_bf16(a2, Bf[2][0], c0, 0, 0, 0);
        c1 = __builtin_amdgcn_mfma_f32_16x16x32_bf16(a2, Bf[2][1], c1, 0, 0, 0);
        c0 = __builtin_amdgcn_mfma_f32_16x16x32_bf16(a3, Bf[3][0], c0, 0, 0, 0);
        c1 = __builtin_amdgcn_mfma_f32_16x16x32_bf16(a3, Bf[3][1], c1, 0, 0, 0);

        float cpre = (g & 1) ? c1[0] : c0[0];  // all C rows equal; reg0 suffices
        float cand = isB ? cpre : __expf(ft) * cpre;
        x = mt ? cand : x;

        if ((r & 7) == 7) {
            // barrier-free rescale: every wave sums the SAME published image
            // (identical values + order -> identical exponent on all waves)
            float s = 0.f;
#pragma unroll
            for (int i = 0; i < 8; ++i)
                s += bf2f(a0[i]) + bf2f(a1[i]) + bf2f(a2[i]) + bf2f(a3[i]);
            s += swzf<0x401F>(s);      // xor 16: combine the 4 k-chunk groups
            s += __shfl_xor(s, 32);
            int ex;
            frexpf(s, &ex);
            x = ldexpf(x, -ex);        // exact power-of-2: no rounding error
            eacc += ex;
        }
    }

    // ---- export final vectors + exponents ----
    if (g < 2) { (isB ? bv : av)[b * LL + p_own] = x; }
    if (tid == 0) { (isB ? eBa : eFa)[b] = (float)eacc; }

    // ---- numerator (gold path, fp32 exact) in the bwd block ----
    if (isB) {
        const int* lb = labels + b * SS;
        const int* mb = mask + b * SS;
        float term = 0.f;
        int cnt = 0;
#pragma unroll
        for (int rr = 0; rr < 2; ++rr) {
            int tt = tid + rr * 256;
            int l = lb[tt];
            if ((unsigned)l >= LL) l = 0;
            int m = mb[tt];
            cnt += (m != 0);
            if (tt == 0) {
                term += start_t[l] + fb[l];
            } else if (m) {
                int lp = lb[tt - 1];
                if ((unsigned)lp >= LL) lp = 0;
                term += trans[lp * LL + l] + fb[(size_t)tt * LL + l];
            }
        }
#pragma unroll
        for (int o = 1; o < 64; o <<= 1) {
            term += __shfl_xor(term, o);
            cnt += __shfl_xor(cnt, o);
        }
        if (L == 0) { nred[w] = term; cred[w] = cnt; }
        __syncthreads();
        if (tid == 0) {
            float tot = nred[0] + nred[1] + nred[2] + nred[3];
            int c = cred[0] + cred[1] + cred[2] + cred[3];
            int sl = c - 1;
            sl = sl < 0 ? 0 : (sl >= SS ? SS - 1 : sl);
            int lt = lb[sl];
            if ((unsigned)lt >= LL) lt = 0;
            lognum[b] = tot + end_t[lt];
        }
    }
}

// Combine: Z = sum_i alpha_255[i]*beta_255[i] * 2^(eF+eB); loss reduce.
__global__ __launch_bounds__(256) void crf_final_kernel(
    const float* __restrict__ ws, const float* __restrict__ conf,
    float* __restrict__ out)
{
    const int tid = threadIdx.x;  // = batch index
    const float* av = ws;
    const float* bv = ws + NB * LL;
    const float* eFa = ws + 2 * NB * LL;
    const float* eBa = eFa + NB;
    const float* ln = eBa + NB;

    const float4* a4 = (const float4*)(av + tid * LL);
    const float4* b4 = (const float4*)(bv + tid * LL);
    float dot = 0.f;
#pragma unroll 8
    for (int k = 0; k < 32; ++k) {
        float4 a = a4[k], bb = b4[k];
        dot += a.x * bb.x + a.y * bb.y + a.z * bb.z + a.w * bb.w;
    }
    float logZ = logf(dot) + 0.69314718055994531f * (eFa[tid] + eBa[tid]);
    float loss = (logZ - ln[tid]) * conf[tid] * (1.0f / NB);

#pragma unroll
    for (int o = 1; o < 64; o <<= 1) loss += __shfl_xor(loss, o);
    __shared__ float red[4];
    if ((tid & 63) == 0) red[tid >> 6] = loss;
    __syncthreads();
    if (tid == 0) out[0] = red[0] + red[1] + red[2] + red[3];
}

extern "C" void kernel_launch(void* const* d_in, const int* in_sizes, int n_in,
                              void* d_out, int out_size, void* d_ws, size_t ws_size,
                              hipStream_t stream) {
    const float* feats  = (const float*)d_in[0];
    const float* startt = (const float*)d_in[1];
    const float* endt   = (const float*)d_in[2];
    const float* trans  = (const float*)d_in[3];
    const float* conf   = (const float*)d_in[4];
    const int*   mask   = (const int*)d_in[5];
    const int*   labels = (const int*)d_in[6];
    float* out = (float*)d_out;
    float* ws = (float*)d_ws;  // needs (2*256*128 + 3*256) floats = ~266 KB

    hipLaunchKernelGGL(crf_chain_kernel, dim3(2 * NB), dim3(256), 0, stream,
                       feats, startt, endt, trans, mask, labels, ws);
    hipLaunchKernelGGL(crf_final_kernel, dim3(1), dim3(256), 0, stream,
                       ws, conf, out);
}